// Round 6
// baseline (337.671 us; speedup 1.0000x reference)
//
#include <hip/hip_runtime.h>

#define QLEN 2048
#define BSZ  2
#define NH   12
#define DH   64
#define DM   768
#define HID  2304
#define SCALE 0.125f
#define RELROWS 2176     // 2048 + 128 zero pad
#define PADT2 152        // T strip row stride (bf16 elems)

typedef __attribute__((ext_vector_type(8))) short short8;
typedef __attribute__((ext_vector_type(4))) float f32x4;
typedef __attribute__((ext_vector_type(4))) int i32x4;
typedef unsigned short ushort_t;

static __device__ __forceinline__ ushort_t f2bf(float x) {
  unsigned u = __float_as_uint(x);
  return (ushort_t)((u + 0x7FFFu + ((u >> 16) & 1u)) >> 16);
}
static __device__ __forceinline__ float bf2f(ushort_t h) {
  return __uint_as_float(((unsigned)h) << 16);
}
static __device__ __forceinline__ unsigned cvt_pk_bf16(float lo, float hi) {
  unsigned r;
  asm("v_cvt_pk_bf16_f32 %0, %1, %2" : "=v"(r) : "v"(lo), "v"(hi));
  return r;
}

// ---------------------------------------------------------------------------
// Kernel 1: QKV projection, bf16 MFMA, f32 inputs (pack fused into staging).
// Q part pre-scaled by SCALE.  Outputs bf16 [b][n][i|j][d].
// ---------------------------------------------------------------------------
__global__ __launch_bounds__(256)
void qkv_mfma(const float* __restrict__ A, const float* __restrict__ B,
              ushort_t* __restrict__ Qo, ushort_t* __restrict__ Ko,
              ushort_t* __restrict__ Vo) {
  __shared__ __align__(16) ushort_t As[128*64];
  __shared__ __align__(16) ushort_t Bs[128*64];
  const int bx = blockIdx.x;        // 18 N-tiles
  const int by = blockIdx.y;        // 32 M-tiles
  const int rbase = by*128, cbase = bx*128;
  const int tid = threadIdx.x;
  const int wv = tid>>6, lane = tid&63, lrow = lane>>4, lcol = lane&15;
  const int wr = wv>>1, wc = wv&1;
  const int sr = tid>>3, sc = tid&7;

  f32x4 acc[4][4];
  #pragma unroll
  for (int m = 0; m < 4; ++m)
    #pragma unroll
    for (int nn = 0; nn < 4; ++nn)
      acc[m][nn] = (f32x4){0.f,0.f,0.f,0.f};

  for (int kk = 0; kk < DM; kk += 64) {
    __syncthreads();
    #pragma unroll
    for (int q = 0; q < 4; ++q) {
      const int row = sr + 32*q;
      const float4 a0 = *(const float4*)&A[(size_t)(rbase+row)*DM + kk + sc*8];
      const float4 a1 = *(const float4*)&A[(size_t)(rbase+row)*DM + kk + sc*8 + 4];
      i32x4 va = { (int)cvt_pk_bf16(a0.x,a0.y), (int)cvt_pk_bf16(a0.z,a0.w),
                   (int)cvt_pk_bf16(a1.x,a1.y), (int)cvt_pk_bf16(a1.z,a1.w) };
      *(short8*)((char*)As + row*128 + ((sc*16) ^ ((row&7)<<4))) = __builtin_bit_cast(short8, va);
      const float4 b0 = *(const float4*)&B[(size_t)(cbase+row)*DM + kk + sc*8];
      const float4 b1 = *(const float4*)&B[(size_t)(cbase+row)*DM + kk + sc*8 + 4];
      i32x4 vb = { (int)cvt_pk_bf16(b0.x,b0.y), (int)cvt_pk_bf16(b0.z,b0.w),
                   (int)cvt_pk_bf16(b1.x,b1.y), (int)cvt_pk_bf16(b1.z,b1.w) };
      *(short8*)((char*)Bs + row*128 + ((sc*16) ^ ((row&7)<<4))) = __builtin_bit_cast(short8, vb);
    }
    __syncthreads();
    short8 af[4][2], bfr[4][2];
    #pragma unroll
    for (int m = 0; m < 4; ++m) {
      const int row = wr*64 + m*16 + lcol;
      af[m][0] = *(const short8*)((const char*)As + row*128 + (((     lrow*16)) ^ ((row&7)<<4)));
      af[m][1] = *(const short8*)((const char*)As + row*128 + (((64 + lrow*16)) ^ ((row&7)<<4)));
    }
    #pragma unroll
    for (int nn = 0; nn < 4; ++nn) {
      const int row = wc*64 + nn*16 + lcol;
      bfr[nn][0] = *(const short8*)((const char*)Bs + row*128 + (((     lrow*16)) ^ ((row&7)<<4)));
      bfr[nn][1] = *(const short8*)((const char*)Bs + row*128 + (((64 + lrow*16)) ^ ((row&7)<<4)));
    }
    #pragma unroll
    for (int m = 0; m < 4; ++m)
      #pragma unroll
      for (int nn = 0; nn < 4; ++nn) {
        acc[m][nn] = __builtin_amdgcn_mfma_f32_16x16x32_bf16(af[m][0], bfr[nn][0], acc[m][nn], 0, 0, 0);
        acc[m][nn] = __builtin_amdgcn_mfma_f32_16x16x32_bf16(af[m][1], bfr[nn][1], acc[m][nn], 0, 0, 0);
      }
  }
  const int part = cbase / DM;      // uniform per block
  ushort_t* dst = (part == 0) ? Qo : ((part == 1) ? Ko : Vo);
  const float sc2 = (part == 0) ? SCALE : 1.0f;   // pre-scale Q
  #pragma unroll
  for (int nn = 0; nn < 4; ++nn) {
    const int h  = cbase - part*DM + wc*64 + nn*16;
    const int nh = h >> 6;
    const int d  = (h & 63) + lcol;
    #pragma unroll
    for (int m = 0; m < 4; ++m)
      #pragma unroll
      for (int reg = 0; reg < 4; ++reg) {
        const int r = rbase + wr*64 + m*16 + lrow*4 + reg;
        const int i = r >> 1, b = r & 1;
        dst[((size_t)(b*NH + nh)*QLEN + i)*DH + d] = f2bf(acc[m][nn][reg] * sc2);
      }
  }
}

// ---------------------------------------------------------------------------
// Kernel 2: V bf16 [bn][j][d] -> Vt bf16 [bn][d][j]  (LDS transpose)
// ---------------------------------------------------------------------------
__global__ __launch_bounds__(256)
void vt_pack(const ushort_t* __restrict__ V, ushort_t* __restrict__ Vt) {
  __shared__ ushort_t Ls[64][72];
  const int jt = blockIdx.x, bn = blockIdx.y;
  const int tid = threadIdx.x;
  const size_t base = (size_t)bn * (QLEN*DH);
  #pragma unroll
  for (int q = 0; q < 2; ++q) {
    const int row = (tid>>3) + 32*q;
    const int c8  = (tid&7)*8;
    *(short8*)&Ls[row][c8] = *(const short8*)&V[base + (size_t)(jt*64+row)*DH + c8];
  }
  __syncthreads();
  #pragma unroll
  for (int q = 0; q < 2; ++q) {
    const int d  = (tid>>3) + 32*q;
    const int j8 = (tid&7)*8;
    short8 o;
    #pragma unroll
    for (int e = 0; e < 8; ++e) o[e] = (short)Ls[j8+e][d];
    *(short8*)&Vt[base + (size_t)d*QLEN + jt*64 + j8] = o;
  }
}

// ---------------------------------------------------------------------------
// Kernel 3: pack r_emb -> RELp bf16 [n][g][d] (zero pad); rbias*SCALE -> rbp
// ---------------------------------------------------------------------------
__global__ __launch_bounds__(256)
void rel_pack(const float* __restrict__ remb, const float* __restrict__ rbias,
              ushort_t* __restrict__ RELp, float* __restrict__ rbp) {
  const int n = blockIdx.y;
  const int g = blockIdx.x*4 + (threadIdx.x >> 6);
  const int d = threadIdx.x & 63;
  const bool ok = g < QLEN;
  const float v = ok ? remb[((size_t)g*NH + n)*DH + d] : 0.f;
  RELp[((size_t)n*RELROWS + g)*DH + d] = f2bf(v);
  if (d == 0) rbp[n*RELROWS + g] = (ok ? rbias[g*NH + n] : 0.f) * SCALE;
}

// ---------------------------------------------------------------------------
// Kernel 4: KB[b,n,j] = dot(r_w_bias[n], K[b,n,j,:]) * SCALE
// ---------------------------------------------------------------------------
__global__ __launch_bounds__(256)
void kbias_kernel(const ushort_t* __restrict__ K, const float* __restrict__ rwb,
                  float* __restrict__ KB) {
  const int wv = threadIdx.x >> 6, lane = threadIdx.x & 63;
  const int row = blockIdx.x*4 + wv;             // (b*NH+n)*QLEN + j
  const int n = (row >> 11) % NH;
  float v = bf2f(K[(size_t)row*DH + lane]) * rwb[n*DH + lane];
  #pragma unroll
  for (int o = 32; o > 0; o >>= 1) v += __shfl_xor(v, o, 64);
  if (lane == 0) KB[row] = v * SCALE;
}

// ---------------------------------------------------------------------------
// Kernel 5: MFMA flash attention, swapped-S + in-register P redistribution.
// grid = (128 q-tiles of 16 rows [reversed], 24 bn), block = 256 (4 waves).
// All 4 waves share 16 q-rows; wave w handles key-tiles t = w, w+4, ... of
// 128 keys (NT = it16/8+1 <= 16 => <= 4 iters/wave).  Swapped QK^T
// (mfma(K,Q)): lane holds S[q=lcol][key=cb*16+lrow*4+reg]; softmax state is
// per-lane scalar (q=lcol); P->A-fragment for PV via 16 cvt_pk + 32 shfl
// (no P LDS).  T strip kept in wave-private LDS (non-swapped orientation).
// Cross-wave merge of (m,l,acc) in LDS at the end.
// ---------------------------------------------------------------------------
#define TW_BYTES (16*PADT2*2)          // 4864 per wave
#define SMEM_A   (4*TW_BYTES)          // 19456; merge overlay 64*68*4+512 fits

__global__ __launch_bounds__(256, 5)
void attn_kernel(const ushort_t* __restrict__ Qb,
                 const ushort_t* __restrict__ Kb,
                 const ushort_t* __restrict__ Vt,
                 const ushort_t* __restrict__ RELp,
                 const float* __restrict__ rbp,
                 const float* __restrict__ KB,
                 ushort_t* __restrict__ AV) {
  __shared__ __align__(16) char smem[SMEM_A];
  const int it16 = 127 - blockIdx.x;      // heavy tiles dispatch first
  const int bn   = blockIdx.y;
  const int n    = bn % NH;
  const int tid  = threadIdx.x;
  const int wv = tid >> 6, lane = tid & 63;
  const int lrow = lane >> 4, lcol = lane & 15;
  const int ib = it16*16;
  const size_t base = (size_t)bn * (QLEN*DH);
  ushort_t* Tw = (ushort_t*)(smem + wv*TW_BYTES);

  const int qi = ib + lcol;
  const short8 qf0 = *(const short8*)&Qb[base + (size_t)qi*DH + lrow*8];
  const short8 qf1 = *(const short8*)&Qb[base + (size_t)qi*DH + 32 + lrow*8];

  f32x4 accO[4];
  float mreg = -3.0e38f, lreg = 0.f;
  #pragma unroll
  for (int r = 0; r < 4; ++r) accO[r] = (f32x4){0.f,0.f,0.f,0.f};

  const int NT = (it16 >> 3) + 1;
  for (int t = wv; t < NT; t += 4) {
    const int j0 = t*128;
    const int gbase = 2032 + j0 - ib;
    // ---- T strip = Qs*REL^T + rbias (9 col-blocks) -> wave-private LDS ----
    #pragma unroll
    for (int cb = 0; cb < 9; ++cb) {
      const int g = gbase + cb*16 + lcol;               // in [0, 2176)
      const size_t ro = ((size_t)n*RELROWS + g)*DH + lrow*8;
      const short8 r0 = *(const short8*)&RELp[ro];
      const short8 r1 = *(const short8*)&RELp[ro + 32];
      f32x4 tt = (f32x4){0.f,0.f,0.f,0.f};
      tt = __builtin_amdgcn_mfma_f32_16x16x32_bf16(qf0, r0, tt, 0, 0, 0);
      tt = __builtin_amdgcn_mfma_f32_16x16x32_bf16(qf1, r1, tt, 0, 0, 0);
      const float rb = rbp[n*RELROWS + g];
      #pragma unroll
      for (int reg = 0; reg < 4; ++reg)
        Tw[(lrow*4 + reg)*PADT2 + cb*16 + lcol] = f2bf(tt[reg] + rb);
    }
    // ---- S^T = K * Qs^T (swapped): lane holds S[q=lcol][key=cb*16+lrow*4+reg]
    f32x4 s[8];
    #pragma unroll
    for (int cb = 0; cb < 8; ++cb) {
      const size_t ko = base + (size_t)(j0 + cb*16 + lcol)*DH + lrow*8;
      const short8 k0 = *(const short8*)&Kb[ko];
      const short8 k1 = *(const short8*)&Kb[ko + 32];
      f32x4 a = (f32x4){0.f,0.f,0.f,0.f};
      a = __builtin_amdgcn_mfma_f32_16x16x32_bf16(k0, qf0, a, 0, 0, 0);
      a = __builtin_amdgcn_mfma_f32_16x16x32_bf16(k1, qf1, a, 0, 0, 0);
      s[cb] = a;
    }
    // ---- + T(diag) + KB, causal mask ----
    #pragma unroll
    for (int cb = 0; cb < 8; ++cb) {
      const float4 kb4 = *(const float4*)&KB[bn*QLEN + j0 + cb*16 + lrow*4];
      const float kbr[4] = {kb4.x, kb4.y, kb4.z, kb4.w};
      #pragma unroll
      for (int reg = 0; reg < 4; ++reg) {
        const int kl  = cb*16 + lrow*4 + reg;           // key local
        const int tc  = 15 + kl - lcol;                 // [0, 142]
        const float sv = s[cb][reg] + bf2f(Tw[lcol*PADT2 + tc]) + kbr[reg];
        s[cb][reg] = (j0 + kl > ib + lcol) ? -3.0e38f : sv;
      }
    }
    // ---- online softmax (state per-lane, q = lcol; reduce via xor 16,32) --
    float mx = s[0][0];
    #pragma unroll
    for (int cb = 0; cb < 8; ++cb)
      #pragma unroll
      for (int reg = 0; reg < 4; ++reg) mx = fmaxf(mx, s[cb][reg]);
    mx = fmaxf(mx, __shfl_xor(mx, 16, 64));
    mx = fmaxf(mx, __shfl_xor(mx, 32, 64));
    const float mn = fmaxf(mreg, mx);
    const float al = __expf(mreg - mn);
    mreg = mn;
    float ps = 0.f;
    #pragma unroll
    for (int cb = 0; cb < 8; ++cb)
      #pragma unroll
      for (int reg = 0; reg < 4; ++reg) {
        const float p = __expf(s[cb][reg] - mn);
        s[cb][reg] = p; ps += p;
      }
    ps += __shfl_xor(ps, 16, 64);
    ps += __shfl_xor(ps, 32, 64);
    lreg = lreg*al + ps;
    // ---- rescale accO (accO rows are q = lrow*4+reg; al lives at q = lcol)
    float alq[4];
    #pragma unroll
    for (int reg = 0; reg < 4; ++reg)
      alq[reg] = __shfl(al, (lane & 48) | (lrow*4 + reg), 64);
    #pragma unroll
    for (int cb = 0; cb < 4; ++cb)
      #pragma unroll
      for (int reg = 0; reg < 4; ++reg) accO[cb][reg] *= alq[reg];
    // ---- pack P to bf16 pairs (per-lane, q = lcol) ----
    unsigned pk[8][2];
    #pragma unroll
    for (int cb = 0; cb < 8; ++cb) {
      pk[cb][0] = cvt_pk_bf16(s[cb][0], s[cb][1]);
      pk[cb][1] = cvt_pk_bf16(s[cb][2], s[cb][3]);
    }
    // ---- redistribute to PV A-fragments + MFMA ----
    const int srcA = ((lrow & 1) << 5) + lcol;   // lane (2*(lrow&1), lcol)
    const int srcB = srcA + 16;
    const bool hi = (lrow >> 1) != 0;
    #pragma unroll
    for (int ks = 0; ks < 4; ++ks) {
      const unsigned wa0 = (unsigned)__shfl((int)pk[2*ks  ][0], srcA, 64);
      const unsigned wb0 = (unsigned)__shfl((int)pk[2*ks+1][0], srcA, 64);
      const unsigned wa1 = (unsigned)__shfl((int)pk[2*ks  ][1], srcA, 64);
      const unsigned wb1 = (unsigned)__shfl((int)pk[2*ks+1][1], srcA, 64);
      const unsigned wa2 = (unsigned)__shfl((int)pk[2*ks  ][0], srcB, 64);
      const unsigned wb2 = (unsigned)__shfl((int)pk[2*ks+1][0], srcB, 64);
      const unsigned wa3 = (unsigned)__shfl((int)pk[2*ks  ][1], srcB, 64);
      const unsigned wb3 = (unsigned)__shfl((int)pk[2*ks+1][1], srcB, 64);
      i32x4 pw = { (int)(hi ? wb0 : wa0), (int)(hi ? wb1 : wa1),
                   (int)(hi ? wb2 : wa2), (int)(hi ? wb3 : wa3) };
      const short8 pa = __builtin_bit_cast(short8, pw);
      #pragma unroll
      for (int cb = 0; cb < 4; ++cb) {
        const size_t vo = base + (size_t)(cb*16 + lcol)*QLEN + j0 + ks*32 + lrow*8;
        const short8 vf = *(const short8*)&Vt[vo];
        accO[cb] = __builtin_amdgcn_mfma_f32_16x16x32_bf16(pa, vf, accO[cb], 0, 0, 0);
      }
    }
  }
  // ---- cross-wave merge in LDS (overlays T region) ----
  __syncthreads();
  float* Macc = (float*)smem;                        // [64][68]
  float* Mm   = (float*)(smem + 64*68*4);            // [64]
  float* Ml   = Mm + 64;
  #pragma unroll
  for (int reg = 0; reg < 4; ++reg) {
    const int row = wv*16 + lrow*4 + reg;
    #pragma unroll
    for (int cb = 0; cb < 4; ++cb)
      Macc[row*68 + cb*16 + lcol] = accO[cb][reg];
  }
  if (lrow == 0) { Mm[wv*16 + lcol] = mreg; Ml[wv*16 + lcol] = lreg; }
  __syncthreads();
  #pragma unroll
  for (int h = 0; h < 4; ++h) {
    const int o = tid + h*256;
    const int row = o >> 6, col = o & 63;            // row 0..15, col 0..63
    float M = Mm[row];
    #pragma unroll
    for (int w2 = 1; w2 < 4; ++w2) M = fmaxf(M, Mm[w2*16 + row]);
    float L = 0.f, V = 0.f;
    #pragma unroll
    for (int w2 = 0; w2 < 4; ++w2) {
      const float e = __expf(Mm[w2*16 + row] - M);
      L += Ml[w2*16 + row] * e;
      V += Macc[(w2*16 + row)*68 + col] * e;
    }
    AV[base + (size_t)(ib + row)*DH + col] = f2bf(V / L);
  }
}

// ---------------------------------------------------------------------------
// Kernel 6: O-projection, bf16 MFMA; B = o_w f32 (pack fused into staging).
// ---------------------------------------------------------------------------
__global__ __launch_bounds__(256)
void oproj_mfma(const ushort_t* __restrict__ AVp, const float* __restrict__ B,
                float* __restrict__ AO) {
  __shared__ __align__(16) ushort_t As[128*64];
  __shared__ __align__(16) ushort_t Bs[128*64];
  const int bx = blockIdx.x;        // 6 N-tiles
  const int by = blockIdx.y;        // 32 M-tiles
  const int rbase = by*128, cbase = bx*128;
  const int tid = threadIdx.x;
  const int wv = tid>>6, lane = tid&63, lrow = lane>>4, lcol = lane&15;
  const int wr = wv>>1, wc = wv&1;
  const int sr = tid>>3, sc = tid&7;

  f32x4 acc[4][4];
  #pragma unroll
  for (int m = 0; m < 4; ++m)
    #pragma unroll
    for (int nn = 0; nn < 4; ++nn)
      acc[m][nn] = (f32x4){0.f,0.f,0.f,0.f};

  for (int kk = 0; kk < DM; kk += 64) {
    const int nh = kk >> 6;         // head index
    __syncthreads();
    #pragma unroll
    for (int q = 0; q < 4; ++q) {
      const int row = sr + 32*q;
      const int r = rbase + row, i = r >> 1, b = r & 1;
      const short8 va = *(const short8*)&AVp[((size_t)(b*NH + nh)*QLEN + i)*DH + sc*8];
      *(short8*)((char*)As + row*128 + ((sc*16) ^ ((row&7)<<4))) = va;
      const float4 b0 = *(const float4*)&B[(size_t)(cbase+row)*DM + kk + sc*8];
      const float4 b1 = *(const float4*)&B[(size_t)(cbase+row)*DM + kk + sc*8 + 4];
      i32x4 vb = { (int)cvt_pk_bf16(b0.x,b0.y), (int)cvt_pk_bf16(b0.z,b0.w),
                   (int)cvt_pk_bf16(b1.x,b1.y), (int)cvt_pk_bf16(b1.z,b1.w) };
      *(short8*)((char*)Bs + row*128 + ((sc*16) ^ ((row&7)<<4))) = __builtin_bit_cast(short8, vb);
    }
    __syncthreads();
    short8 af[4][2], bfr[4][2];
    #pragma unroll
    for (int m = 0; m < 4; ++m) {
      const int row = wr*64 + m*16 + lcol;
      af[m][0] = *(const short8*)((const char*)As + row*128 + (((     lrow*16)) ^ ((row&7)<<4)));
      af[m][1] = *(const short8*)((const char*)As + row*128 + (((64 + lrow*16)) ^ ((row&7)<<4)));
    }
    #pragma unroll
    for (int nn = 0; nn < 4; ++nn) {
      const int row = wc*64 + nn*16 + lcol;
      bfr[nn][0] = *(const short8*)((const char*)Bs + row*128 + (((     lrow*16)) ^ ((row&7)<<4)));
      bfr[nn][1] = *(const short8*)((const char*)Bs + row*128 + (((64 + lrow*16)) ^ ((row&7)<<4)));
    }
    #pragma unroll
    for (int m = 0; m < 4; ++m)
      #pragma unroll
      for (int nn = 0; nn < 4; ++nn) {
        acc[m][nn] = __builtin_amdgcn_mfma_f32_16x16x32_bf16(af[m][0], bfr[nn][0], acc[m][nn], 0, 0, 0);
        acc[m][nn] = __builtin_amdgcn_mfma_f32_16x16x32_bf16(af[m][1], bfr[nn][1], acc[m][nn], 0, 0, 0);
      }
  }
  #pragma unroll
  for (int nn = 0; nn < 4; ++nn) {
    const int mcol = cbase + wc*64 + nn*16 + lcol;
    #pragma unroll
    for (int mi = 0; mi < 4; ++mi)
      #pragma unroll
      for (int reg = 0; reg < 4; ++reg) {
        const int r = rbase + wr*64 + mi*16 + lrow*4 + reg;
        AO[(size_t)r*DM + mcol] = acc[mi][nn][reg];
      }
  }
}

// ---------------------------------------------------------------------------
// Kernel 7: residual + LayerNorm.
// ---------------------------------------------------------------------------
__global__ __launch_bounds__(256)
void ln_kernel(const float* __restrict__ AO, const float* __restrict__ W,
               const float* __restrict__ gamma, const float* __restrict__ beta,
               float* __restrict__ out) {
  const int r = blockIdx.x;
  const int tid = threadIdx.x;
  const int wv = tid >> 6, lane = tid & 63;
  float x[3];
  #pragma unroll
  for (int q = 0; q < 3; ++q) {
    const int mcol = tid + q*256;
    x[q] = AO[(size_t)r*DM + mcol] + W[(size_t)r*DM + mcol];
  }
  float s1 = x[0] + x[1] + x[2];
  float s2 = x[0]*x[0] + x[1]*x[1] + x[2]*x[2];
  #pragma unroll
  for (int o = 32; o > 0; o >>= 1) { s1 += __shfl_xor(s1, o, 64); s2 += __shfl_xor(s2, o, 64); }
  __shared__ float a1[4], a2[4];
  if (lane == 0) { a1[wv] = s1; a2[wv] = s2; }
  __syncthreads();
  s1 = a1[0] + a1[1] + a1[2] + a1[3];
  s2 = a2[0] + a2[1] + a2[2] + a2[3];
  const float mu  = s1 * (1.0f/DM);
  const float var = s2 * (1.0f/DM) - mu*mu;
  const float rs  = rsqrtf(var + 1e-5f);
  #pragma unroll
  for (int q = 0; q < 3; ++q) {
    const int mcol = tid + q*256;
    out[(size_t)r*DM + mcol] = (x[q] - mu)*rs*gamma[mcol] + beta[mcol];
  }
}

// ---------------------------------------------------------------------------
extern "C" void kernel_launch(void* const* d_in, const int* in_sizes, int n_in,
                              void* d_out, int out_size, void* d_ws, size_t ws_size,
                              hipStream_t stream) {
  const float* w      = (const float*)d_in[0];
  const float* r_emb  = (const float*)d_in[1];
  const float* r_wb   = (const float*)d_in[2];
  const float* r_bias = (const float*)d_in[3];
  const float* qkv_w  = (const float*)d_in[4];
  const float* o_w    = (const float*)d_in[5];
  const float* ln_g   = (const float*)d_in[6];
  const float* ln_b   = (const float*)d_in[7];
  float* out = (float*)d_out;

  const size_t QS = (size_t)BSZ*NH*QLEN*DH;       // 3,145,728 elems
  ushort_t* u     = (ushort_t*)d_ws;
  ushort_t* Vb16  = u;                            // QS  (dead after vt_pack)
  ushort_t* Qb    = Vb16 + QS;
  ushort_t* Kb    = Qb + QS;
  ushort_t* Vt    = Kb + QS;
  ushort_t* AVb16 = Vt + QS;
  ushort_t* RELp  = AVb16 + QS;                   // NH*RELROWS*DH
  float* rbp = (float*)(RELp + (size_t)NH*RELROWS*DH);
  float* KBb = rbp + NH*RELROWS;
  float* AO  = (float*)Qb;                        // QS f32 = Qb+Kb (dead by oproj)

  qkv_mfma<<<dim3(HID/128, (QLEN*BSZ)/128), dim3(256), 0, stream>>>(w, qkv_w, Qb, Kb, Vb16);
  vt_pack<<<dim3(QLEN/64, BSZ*NH), dim3(256), 0, stream>>>(Vb16, Vt);
  rel_pack<<<dim3(RELROWS/4, NH), dim3(256), 0, stream>>>(r_emb, r_bias, RELp, rbp);
  kbias_kernel<<<dim3(BSZ*NH*QLEN/4), dim3(256), 0, stream>>>(Kb, r_wb, KBb);
  attn_kernel<<<dim3(128, BSZ*NH), dim3(256), 0, stream>>>(Qb, Kb, Vt, RELp, rbp, KBb, AVb16);
  oproj_mfma<<<dim3(DM/128, (QLEN*BSZ)/128), dim3(256), 0, stream>>>(AVb16, o_w, AO);
  ln_kernel<<<dim3(QLEN*BSZ), dim3(256), 0, stream>>>(AO, w, ln_g, ln_b, out);
}